// Round 16
// baseline (381.589 us; speedup 1.0000x reference)
//
#include <hip/hip_runtime.h>

#define NE 400000
#define NNODES 25000

typedef __attribute__((ext_vector_type(8))) short short8;
typedef __attribute__((ext_vector_type(4))) float f32x4;

// weight-plane ushort offsets inside wp
#define W2A_H 0
#define W2A_L 24576
#define W2B_H 49152
#define W2B_L 65536
#define W2C_H 81920
#define W2C_L 98304
#define WLIN_H 114688
#define WLIN_L 116736
#define W1_H   118784
#define W1_L   122880

__device__ __forceinline__ unsigned short f2bf(float f) {
  unsigned int u = __float_as_uint(f);
  unsigned int r = u + 0x7fffu + ((u >> 16) & 1u);
  return (unsigned short)(r >> 16);
}
__device__ __forceinline__ float bf2f(unsigned short h) {
  return __uint_as_float(((unsigned int)h) << 16);
}
__device__ __forceinline__ float bf2f_lo(unsigned int u) {
  return __uint_as_float(u << 16);
}
__device__ __forceinline__ float bf2f_hi(unsigned int u) {
  return __uint_as_float(u & 0xFFFF0000u);
}
__device__ __forceinline__ unsigned int cvtpk(float lo, float hi) {
  unsigned int r;
  asm("v_cvt_pk_bf16_f32 %0, %1, %2" : "=v"(r) : "v"(lo), "v"(hi));
  return r;
}
__device__ __forceinline__ float fsilu(float z) {
  return z * __builtin_amdgcn_rcpf(1.f + __expf(-z));
}

// ------------------- hierarchical scan: A (block scans + totals)
__global__ __launch_bounds__(256) void kscanA(const int* __restrict__ cnt,
                                              int* __restrict__ start,
                                              int* __restrict__ sums) {
  __shared__ int wtot[4];
  const int t = threadIdx.x, lane = t & 63, wid = t >> 6;
  const int idx = blockIdx.x * 256 + t;
  int v = (idx < NNODES) ? cnt[idx] : 0;
  int incl = v;
  #pragma unroll
  for (int off = 1; off < 64; off <<= 1) {
    int u = __shfl_up(incl, off, 64);
    if (lane >= off) incl += u;
  }
  if (lane == 63) wtot[wid] = incl;
  __syncthreads();
  int woff = 0;
  #pragma unroll
  for (int i = 0; i < 4; ++i)
    if (i < wid) woff += wtot[i];
  int excl = incl - v + woff;
  if (idx < NNODES) start[idx] = excl;
  if (t == 255) sums[blockIdx.x] = excl + v;
}

// ------------- scan C (merged B): per-block redundant 98-scan + offset apply
__global__ __launch_bounds__(256) void kscanC(const int* __restrict__ sums,
                                              int* __restrict__ start,
                                              int* __restrict__ cursor) {
  __shared__ int ex[128];
  const int t = threadIdx.x, lane = t & 63;
  if (t < 64) {
    int a = (lane < 98) ? sums[lane] : 0;
    int b = (64 + lane < 98) ? sums[64 + lane] : 0;
    int ia = a;
    #pragma unroll
    for (int off = 1; off < 64; off <<= 1) {
      int u = __shfl_up(ia, off, 64);
      if (lane >= off) ia += u;
    }
    int total_a = __shfl(ia, 63, 64);
    int ib = b;
    #pragma unroll
    for (int off = 1; off < 64; off <<= 1) {
      int u = __shfl_up(ib, off, 64);
      if (lane >= off) ib += u;
    }
    ex[lane] = ia - a;
    ex[64 + lane] = total_a + ib - b;
  }
  __syncthreads();
  const int idx = blockIdx.x * 256 + t;
  if (idx < NNODES) {
    int s = start[idx] + ex[blockIdx.x];
    start[idx] = s;
    cursor[idx] = s;
  }
  if (idx == 0) start[NNODES] = NE;
}

// ---------------------------------------------------- CSR build: fill order
__global__ __launch_bounds__(256) void kfill(const int* __restrict__ esrc,
                                             int* __restrict__ cursor,
                                             int* __restrict__ order) {
  int e = blockIdx.x * 256 + threadIdx.x;
  if (e < NE) {
    int p = atomicAdd(&cursor[esrc[e]], 1);
    order[p] = e;
  }
}

// ------- kprep: zero cnt + split weights into fragment-linear planes
__global__ __launch_bounds__(256) void kprep(
    const float* __restrict__ W2a, const float* __restrict__ W2b,
    const float* __restrict__ W2c, const float* __restrict__ Wlin,
    const float* __restrict__ W1, unsigned short* __restrict__ wp,
    int* __restrict__ cnt)
{
  int tid = blockIdx.x * 256 + threadIdx.x;
  for (int i = tid; i < NNODES; i += 7936) cnt[i] = 0;
  if (tid < 7168) {
    int gi = tid;
    const float* W; float sc; unsigned short* outh; int K;
    if (gi < 3072)      { W = W2a; sc = 0.07216878364870323f; outh = wp + W2A_H; K = 192; }
    else if (gi < 5120) { W = W2b; sc = 0.08838834764831845f; outh = wp + W2B_H; K = 128; gi -= 3072; }
    else                { W = W2c; sc = 0.08838834764831845f; outh = wp + W2C_H; K = 128; gi -= 5120; }
    unsigned short* outl = outh + K * 128;
    int l15 = gi & 15, l4 = (gi >> 4) & 3, c16 = (gi >> 6) & 7, kc5 = gi >> 9;
    #pragma unroll
    for (int j = 0; j < 8; ++j) {
      int k = kc5 * 32 + l4 * 8 + j;
      int n = c16 * 16 + l15;
      float v = W[(size_t)k * 128 + n] * sc;
      unsigned short h = f2bf(v);
      outh[gi * 8 + j] = h;
      outl[gi * 8 + j] = f2bf(v - bf2f(h));
    }
  } else if (tid < 7424) {
    int gi = tid - 7168;
    int l15 = gi & 15, l4 = (gi >> 4) & 3, nt = (gi >> 6) & 1, kc2 = gi >> 7;
    #pragma unroll
    for (int j = 0; j < 8; ++j) {
      int k = kc2 * 32 + l4 * 8 + j;
      int n = nt * 16 + l15;
      float v = Wlin[(size_t)k * 32 + n] * 0.125f;
      unsigned short h = f2bf(v);
      wp[WLIN_H + gi * 8 + j] = h;
      wp[WLIN_L + gi * 8 + j] = f2bf(v - bf2f(h));
    }
  } else if (tid < 7936) {
    int gi = tid - 7424;  // W1: 128 x 32, scale 1/sqrt(128)
    int l15 = gi & 15, l4 = (gi >> 4) & 3, nf = (gi >> 6) & 1, kc5 = gi >> 7;
    #pragma unroll
    for (int j = 0; j < 8; ++j) {
      int k = kc5 * 32 + l4 * 8 + j;
      int n = nf * 16 + l15;
      float v = W1[(size_t)k * 32 + n] * 0.08838834764831845f;
      unsigned short h = f2bf(v);
      wp[W1_H + gi * 8 + j] = h;
      wp[W1_L + gi * 8 + j] = f2bf(v - bf2f(h));
    }
  }
}

// -------- k1w: histogram + (w = x@W1/sqrt(128)) via 3-product MFMA (no LDS);
//          w stored bf16; also emits xh hi-plane fragments.
__global__ __launch_bounds__(256) void k1w(
    const float* __restrict__ x, const unsigned short* __restrict__ wp,
    const int* __restrict__ esrc, int* __restrict__ cnt,
    unsigned short* __restrict__ wbufh, unsigned short* __restrict__ xh)
{
  const int t = threadIdx.x;
  const int w = t >> 6, lane = t & 63;
  const int l15 = lane & 15, l4 = lane >> 4;
  const int e0 = blockIdx.x * 128;

  if (t < 128) atomicAdd(&cnt[esrc[e0 + t]], 1);

  f32x4 acc[2][2];
  #pragma unroll
  for (int i = 0; i < 2; ++i)
    #pragma unroll
    for (int j = 0; j < 2; ++j) acc[i][j] = (f32x4)(0.f);

  #pragma unroll
  for (int kc5 = 0; kc5 < 4; ++kc5) {
    short8 bh[2], bl[2];
    #pragma unroll
    for (int nf = 0; nf < 2; ++nf) {
      int idx = (((kc5 * 2 + nf) * 4 + l4) * 16 + l15) * 8;
      bh[nf] = *(const short8*)&wp[W1_H + idx];
      bl[nf] = *(const short8*)&wp[W1_L + idx];
    }
    #pragma unroll
    for (int mf = 0; mf < 2; ++mf) {
      const int row = w * 32 + mf * 16 + l15;
      const float* xp = x + (size_t)(e0 + row) * 128 + kc5 * 32 + l4 * 8;
      float a8[8];
      *(float4*)&a8[0] = *(const float4*)xp;
      *(float4*)&a8[4] = *(const float4*)(xp + 4);
      short8 ah, al;
      #pragma unroll
      for (int j = 0; j < 8; ++j) {
        unsigned short h = f2bf(a8[j]);
        ah[j] = (short)h;
        al[j] = (short)f2bf(a8[j] - bf2f(h));
      }
      *(uint4*)&xh[(size_t)blockIdx.x * 16384 + kc5 * 4096 +
                   (w * 2 + mf) * 512 + l4 * 128 + l15 * 8] = *(uint4*)&ah;
      #pragma unroll
      for (int nf = 0; nf < 2; ++nf) {
        acc[mf][nf] = __builtin_amdgcn_mfma_f32_16x16x32_bf16(ah, bh[nf], acc[mf][nf], 0, 0, 0);
        acc[mf][nf] = __builtin_amdgcn_mfma_f32_16x16x32_bf16(ah, bl[nf], acc[mf][nf], 0, 0, 0);
        acc[mf][nf] = __builtin_amdgcn_mfma_f32_16x16x32_bf16(al, bh[nf], acc[mf][nf], 0, 0, 0);
      }
    }
  }
  #pragma unroll
  for (int mf = 0; mf < 2; ++mf)
    #pragma unroll
    for (int nf = 0; nf < 2; ++nf)
      #pragma unroll
      for (int rr = 0; rr < 4; ++rr) {
        int row = e0 + w * 32 + mf * 16 + l4 * 4 + rr;
        wbufh[(size_t)row * 32 + nf * 16 + l15] = f2bf(acc[mf][nf][rr]);
      }
}

// ---- k_agg: per-node gather reduction (1 wave/node); agg stored packed bf16
__global__ __launch_bounds__(64) void k_agg(
    const unsigned short* __restrict__ wbufh, const float* __restrict__ Y,
    const int* __restrict__ start, const int* __restrict__ order,
    unsigned short* __restrict__ aggh)
{
  const int n = blockIdx.x;
  const int t = threadIdx.x;
  const int c = t & 31;
  const int dh = t >> 5;
  const int s0 = start[n], s1 = start[n + 1];
  float a0 = 0.f, a1 = 0.f;
  for (int i = s0; i < s1; ++i) {
    int e = order[i];
    float wv = bf2f(wbufh[(size_t)e * 32 + c]);
    float y0 = Y[e * 4 + dh * 2 + 0];
    float y1 = Y[e * 4 + dh * 2 + 1];
    a0 += wv * y0;
    a1 += wv * y1;
  }
  *(unsigned int*)&aggh[(size_t)n * 128 + c * 4 + dh * 2] = cvtpk(a0, a1);
}

// =================== fused: mix + vout + 3-stage MLP + env ===================
// BM=64, 4 waves, wave tile 32x64. LDS 32 KB in two 16 KB regions, 3 barriers.
// __launch_bounds__(256,5): force <=102 unified regs -> 5 waves/SIMD.
// aggh gather hoisted (the long-latency chain); V loads inline.
__global__ __launch_bounds__(256, 5) void kfused(
    const unsigned short* __restrict__ xh, const float* __restrict__ V,
    const float* __restrict__ r, const int* __restrict__ esrc,
    const unsigned short* __restrict__ aggh, const unsigned short* __restrict__ wp,
    float* __restrict__ xout, float* __restrict__ vout)
{
  __shared__ __align__(16) char lds[32768];

  const int t = threadIdx.x;
  const int w = t >> 6, lane = t & 63;
  const int wr = w >> 1, wc = w & 1;
  const int l15 = lane & 15, l4 = lane >> 4;
  const int e0 = blockIdx.x * 64;
  const size_t T16 = (size_t)(blockIdx.x >> 1) * 16384;
  const int xb1 = blockIdx.x & 1;

  // ---------------- phase A: tensor-product mix (scal -> LDS A, vout -> global)
  {
    const int er = w * 16 + l15;
    const int e = e0 + er;
    const int src = esrc[e];

    // hoist the agg gather for both kc2 chunks (long-latency chain)
    uint4 qa[2][2];
    #pragma unroll
    for (int kc2 = 0; kc2 < 2; ++kc2) {
      const unsigned int* ap =
          (const unsigned int*)(aggh + (size_t)src * 128 + kc2 * 64 + l4 * 16);
      qa[kc2][0] = *(const uint4*)ap;
      qa[kc2][1] = *(const uint4*)(ap + 4);
    }

    f32x4 accv[3][2];
    #pragma unroll
    for (int i = 0; i < 3; ++i)
      #pragma unroll
      for (int nt = 0; nt < 2; ++nt) accv[i][nt] = (f32x4)(0.f);

    #pragma unroll
    for (int kc2 = 0; kc2 < 2; ++kc2) {
      short8 WhF[2], WlF[2];
      #pragma unroll
      for (int nt = 0; nt < 2; ++nt) {
        int idx = ((((kc2 * 2 + nt) * 4 + l4) * 16) + l15) * 8;
        WhF[nt] = *(const short8*)&wp[WLIN_H + idx];
        WlF[nt] = *(const short8*)&wp[WLIN_L + idx];
      }
      float4 av4[4], bv4[4];
      const float* bp = V + (size_t)e * 128 + kc2 * 64 + l4 * 16;
      {
        unsigned int uu[8];
        *(uint4*)&uu[0] = qa[kc2][0];
        *(uint4*)&uu[4] = qa[kc2][1];
        #pragma unroll
        for (int ch = 0; ch < 4; ++ch) {
          bv4[ch] = *(const float4*)(bp + ch * 4);
          av4[ch].x = bf2f_lo(uu[2 * ch]) * 0.25f;
          av4[ch].y = bf2f_hi(uu[2 * ch]) * 0.25f;
          av4[ch].z = bf2f_lo(uu[2 * ch + 1]) * 0.25f;
          av4[ch].w = bf2f_hi(uu[2 * ch + 1]) * 0.25f;
        }
      }
      unsigned int su[4];
      #pragma unroll
      for (int ch = 0; ch < 4; ++ch) {
        float s1 = av4[ch].x * bv4[ch].x;
        float s2 = (av4[ch].y * bv4[ch].y + av4[ch].z * bv4[ch].z +
                    av4[ch].w * bv4[ch].w) * 0.5773502691896258f;
        su[ch] = cvtpk(s1, s2);
      }
      {
        int byte = er * 256 + (kc2 * 32 + l4 * 8) * 2;
        byte ^= (er & 7) << 4;
        *(uint4*)(lds + byte) = *(uint4*)su;
      }
      #pragma unroll
      for (int i = 0; i < 3; ++i) {
        union { unsigned int u[4]; short8 s; } ahu;
        #pragma unroll
        for (int ch = 0; ch < 4; ++ch) {
          float bvi = (i == 0) ? bv4[ch].y : (i == 1) ? bv4[ch].z : bv4[ch].w;
          float avi = (i == 0) ? av4[ch].y : (i == 1) ? av4[ch].z : av4[ch].w;
          ahu.u[ch] = cvtpk(av4[ch].x * bvi, avi * bv4[ch].x);  // (v1, v2)
        }
        #pragma unroll
        for (int nt = 0; nt < 2; ++nt) {
          accv[i][nt] = __builtin_amdgcn_mfma_f32_16x16x32_bf16(ahu.s, WhF[nt], accv[i][nt], 0, 0, 0);
          accv[i][nt] = __builtin_amdgcn_mfma_f32_16x16x32_bf16(ahu.s, WlF[nt], accv[i][nt], 0, 0, 0);
        }
      }
    }
    const int ebase = e0 + w * 16 + l4 * 4;
    #pragma unroll
    for (int nt = 0; nt < 2; ++nt)
      #pragma unroll
      for (int rr = 0; rr < 4; ++rr) {
        float* vp = vout + (size_t)(ebase + rr) * 96 + (nt * 16 + l15) * 3;
        vp[0] = accv[0][nt][rr];
        vp[1] = accv[1][nt][rr];
        vp[2] = accv[2][nt][rr];
      }
  }

  __syncthreads();  // #1: scal visible

  f32x4 acc[2][4];
  const int c16 = wc * 4;

  // ---------------- stage 1: h1 = silu(concat(x, scal) @ W2a / sqrt(192))
  #pragma unroll
  for (int i = 0; i < 2; ++i)
    #pragma unroll
    for (int j = 0; j < 4; ++j) acc[i][j] = (f32x4)(0.f);

  #pragma unroll
  for (int kc5 = 0; kc5 < 6; ++kc5) {
    short8 bh[4];
    #pragma unroll
    for (int nf = 0; nf < 4; ++nf) {
      int idx = (((kc5 * 8 + c16 + nf) * 4 + l4) * 16 + l15) * 8;
      bh[nf] = *(const short8*)&wp[W2A_H + idx];
    }
    #pragma unroll
    for (int mf = 0; mf < 2; ++mf) {
      short8 ah;
      if (kc5 < 4) {
        ah = *(const short8*)&xh[T16 + kc5 * 4096 + xb1 * 2048 +
                                 (wr * 2 + mf) * 512 + l4 * 128 + l15 * 8];
      } else {
        int ar = wr * 32 + mf * 16 + l15;
        int byte = ar * 256 + ((kc5 - 4) * 32 + l4 * 8) * 2;
        byte ^= (ar & 7) << 4;
        ah = *(const short8*)(lds + byte);
      }
      #pragma unroll
      for (int nf = 0; nf < 4; ++nf)
        acc[mf][nf] = __builtin_amdgcn_mfma_f32_16x16x32_bf16(ah, bh[nf], acc[mf][nf], 0, 0, 0);
    }
  }

  // h1 -> region B
  #pragma unroll
  for (int mf = 0; mf < 2; ++mf)
    #pragma unroll
    for (int nf = 0; nf < 4; ++nf)
      #pragma unroll
      for (int rp = 0; rp < 2; ++rp) {
        unsigned int zz = cvtpk(fsilu(acc[mf][nf][2 * rp]), fsilu(acc[mf][nf][2 * rp + 1]));
        #pragma unroll
        for (int rh = 0; rh < 2; ++rh) {
          int row = wr * 32 + mf * 16 + l4 * 4 + 2 * rp + rh;
          int byte = row * 256 + (wc * 64 + nf * 16 + l15) * 2;
          byte ^= (row & 7) << 4;
          *(unsigned short*)(lds + 16384 + byte) = (unsigned short)(zz >> (16 * rh));
        }
      }

  __syncthreads();  // #2: h1 visible

  // ---------------- stage 2: h2 = silu(h1 @ W2b / sqrt(128))
  #pragma unroll
  for (int i = 0; i < 2; ++i)
    #pragma unroll
    for (int j = 0; j < 4; ++j) acc[i][j] = (f32x4)(0.f);

  #pragma unroll
  for (int kc5 = 0; kc5 < 4; ++kc5) {
    short8 bh[4];
    #pragma unroll
    for (int nf = 0; nf < 4; ++nf) {
      int idx = (((kc5 * 8 + c16 + nf) * 4 + l4) * 16 + l15) * 8;
      bh[nf] = *(const short8*)&wp[W2B_H + idx];
    }
    #pragma unroll
    for (int mf = 0; mf < 2; ++mf) {
      int row = wr * 32 + mf * 16 + l15;
      int byte = row * 256 + (kc5 * 32 + l4 * 8) * 2;
      byte ^= (row & 7) << 4;
      short8 ah = *(const short8*)(lds + 16384 + byte);
      #pragma unroll
      for (int nf = 0; nf < 4; ++nf)
        acc[mf][nf] = __builtin_amdgcn_mfma_f32_16x16x32_bf16(ah, bh[nf], acc[mf][nf], 0, 0, 0);
    }
  }

  // h2 -> region A (scal dead)
  #pragma unroll
  for (int mf = 0; mf < 2; ++mf)
    #pragma unroll
    for (int nf = 0; nf < 4; ++nf)
      #pragma unroll
      for (int rp = 0; rp < 2; ++rp) {
        unsigned int zz = cvtpk(fsilu(acc[mf][nf][2 * rp]), fsilu(acc[mf][nf][2 * rp + 1]));
        #pragma unroll
        for (int rh = 0; rh < 2; ++rh) {
          int row = wr * 32 + mf * 16 + l4 * 4 + 2 * rp + rh;
          int byte = row * 256 + (wc * 64 + nf * 16 + l15) * 2;
          byte ^= (row & 7) << 4;
          *(unsigned short*)(lds + byte) = (unsigned short)(zz >> (16 * rh));
        }
      }

  __syncthreads();  // #3: h2 visible

  // ---------------- stage 3: x_out = env(d) * (h2 @ W2c / sqrt(128))
  #pragma unroll
  for (int i = 0; i < 2; ++i)
    #pragma unroll
    for (int j = 0; j < 4; ++j) acc[i][j] = (f32x4)(0.f);

  #pragma unroll
  for (int kc5 = 0; kc5 < 4; ++kc5) {
    short8 bh[4];
    #pragma unroll
    for (int nf = 0; nf < 4; ++nf) {
      int idx = (((kc5 * 8 + c16 + nf) * 4 + l4) * 16 + l15) * 8;
      bh[nf] = *(const short8*)&wp[W2C_H + idx];
    }
    #pragma unroll
    for (int mf = 0; mf < 2; ++mf) {
      int row = wr * 32 + mf * 16 + l15;
      int byte = row * 256 + (kc5 * 32 + l4 * 8) * 2;
      byte ^= (row & 7) << 4;
      short8 ah = *(const short8*)(lds + byte);
      #pragma unroll
      for (int nf = 0; nf < 4; ++nf)
        acc[mf][nf] = __builtin_amdgcn_mfma_f32_16x16x32_bf16(ah, bh[nf], acc[mf][nf], 0, 0, 0);
    }
  }

  #pragma unroll
  for (int mf = 0; mf < 2; ++mf) {
    float env4[4];
    #pragma unroll
    for (int rr = 0; rr < 4; ++rr) {
      int row = e0 + wr * 32 + mf * 16 + l4 * 4 + rr;
      float rx = r[row * 3 + 0];
      float ry = r[row * 3 + 1];
      float rz = r[row * 3 + 2];
      float d2 = rx * rx + ry * ry + rz * rz;
      float d = (d2 == 0.f) ? 1.f : sqrtf(d2);
      float d3 = d * d * d;
      env4[rr] = (d < 1.f) ? (1.f + d3 * d3 * (-28.f + d * (48.f - 21.f * d))) : 0.f;
    }
    #pragma unroll
    for (int nf = 0; nf < 4; ++nf)
      #pragma unroll
      for (int rr = 0; rr < 4; ++rr) {
        int row = e0 + wr * 32 + mf * 16 + l4 * 4 + rr;
        xout[(size_t)row * 128 + wc * 64 + nf * 16 + l15] = acc[mf][nf][rr] * env4[rr];
      }
  }
}

extern "C" void kernel_launch(void* const* d_in, const int* in_sizes, int n_in,
                              void* d_out, int out_size, void* d_ws, size_t ws_size,
                              hipStream_t stream)
{
  const float* x    = (const float*)d_in[0];
  const float* V    = (const float*)d_in[1];
  const float* r    = (const float*)d_in[2];
  const float* Y    = (const float*)d_in[3];
  const int*   es   = (const int*)d_in[4];
  const float* W1   = (const float*)d_in[5];
  const float* W2a  = (const float*)d_in[6];
  const float* W2b  = (const float*)d_in[7];
  const float* W2c  = (const float*)d_in[8];
  const float* Wlin = (const float*)d_in[9];

  float* ws   = (float*)d_ws;
  unsigned short* aggh  = (unsigned short*)ws;             // 3.2M ushort (6.4 MB)
  unsigned short* wbufh = (unsigned short*)(ws + 3200000); // 12.8M ushort
  unsigned short* xh = (unsigned short*)(ws + 16000000);   // 51.2M ushort
  int*   ci   = (int*)(ws + 42000000);
  int*   cnt    = ci;
  int*   startv = ci + 25000;
  int*   cursor = ci + 50008;
  int*   order  = ci + 75008;
  int*   sums   = ci + 480000;                             // 98 ints
  unsigned short* wp = (unsigned short*)(ws + 43000000);   // ~254 KB weight planes
  float* xout = (float*)d_out;
  float* vout = (float*)d_out + 51200000;

  (void)in_sizes; (void)n_in; (void)out_size; (void)ws_size;

  kprep<<<dim3(31), 256, 0, stream>>>(W2a, W2b, W2c, Wlin, W1, wp, cnt);
  k1w<<<dim3(NE / 128), 256, 0, stream>>>(x, wp, es, cnt, wbufh, xh);
  kscanA<<<dim3(98), 256, 0, stream>>>(cnt, startv, sums);
  kscanC<<<dim3(98), 256, 0, stream>>>(sums, startv, cursor);
  kfill<<<dim3((NE + 255) / 256), 256, 0, stream>>>(es, cursor, order);
  k_agg<<<dim3(NNODES), 64, 0, stream>>>(wbufh, Y, startv, order, aggh);
  kfused<<<dim3(NE / 64), 256, 0, stream>>>(xh, V, r, es, aggh, wp, xout, vout);
}

// Round 17
// 366.974 us; speedup vs baseline: 1.0398x; 1.0398x over previous
//
#include <hip/hip_runtime.h>

#define NE 400000
#define NNODES 25000

typedef __attribute__((ext_vector_type(8))) short short8;
typedef __attribute__((ext_vector_type(4))) float f32x4;

// weight-plane ushort offsets inside wp
#define W2A_H 0
#define W2A_L 24576
#define W2B_H 49152
#define W2B_L 65536
#define W2C_H 81920
#define W2C_L 98304
#define WLIN_H 114688
#define WLIN_L 116736
#define W1_H   118784
#define W1_L   122880

__device__ __forceinline__ unsigned short f2bf(float f) {
  unsigned int u = __float_as_uint(f);
  unsigned int r = u + 0x7fffu + ((u >> 16) & 1u);
  return (unsigned short)(r >> 16);
}
__device__ __forceinline__ float bf2f(unsigned short h) {
  return __uint_as_float(((unsigned int)h) << 16);
}
__device__ __forceinline__ float bf2f_lo(unsigned int u) {
  return __uint_as_float(u << 16);
}
__device__ __forceinline__ float bf2f_hi(unsigned int u) {
  return __uint_as_float(u & 0xFFFF0000u);
}
__device__ __forceinline__ unsigned int cvtpk(float lo, float hi) {
  unsigned int r;
  asm("v_cvt_pk_bf16_f32 %0, %1, %2" : "=v"(r) : "v"(lo), "v"(hi));
  return r;
}
__device__ __forceinline__ float fsilu(float z) {
  return z * __builtin_amdgcn_rcpf(1.f + __expf(-z));
}

// ------------------- hierarchical scan: A (block scans + totals)
__global__ __launch_bounds__(256) void kscanA(const int* __restrict__ cnt,
                                              int* __restrict__ start,
                                              int* __restrict__ sums) {
  __shared__ int wtot[4];
  const int t = threadIdx.x, lane = t & 63, wid = t >> 6;
  const int idx = blockIdx.x * 256 + t;
  int v = (idx < NNODES) ? cnt[idx] : 0;
  int incl = v;
  #pragma unroll
  for (int off = 1; off < 64; off <<= 1) {
    int u = __shfl_up(incl, off, 64);
    if (lane >= off) incl += u;
  }
  if (lane == 63) wtot[wid] = incl;
  __syncthreads();
  int woff = 0;
  #pragma unroll
  for (int i = 0; i < 4; ++i)
    if (i < wid) woff += wtot[i];
  int excl = incl - v + woff;
  if (idx < NNODES) start[idx] = excl;
  if (t == 255) sums[blockIdx.x] = excl + v;
}

// ------------- scan C (merged B): per-block redundant 98-scan + offset apply
__global__ __launch_bounds__(256) void kscanC(const int* __restrict__ sums,
                                              int* __restrict__ start,
                                              int* __restrict__ cursor) {
  __shared__ int ex[128];
  const int t = threadIdx.x, lane = t & 63;
  if (t < 64) {
    int a = (lane < 98) ? sums[lane] : 0;
    int b = (64 + lane < 98) ? sums[64 + lane] : 0;
    int ia = a;
    #pragma unroll
    for (int off = 1; off < 64; off <<= 1) {
      int u = __shfl_up(ia, off, 64);
      if (lane >= off) ia += u;
    }
    int total_a = __shfl(ia, 63, 64);
    int ib = b;
    #pragma unroll
    for (int off = 1; off < 64; off <<= 1) {
      int u = __shfl_up(ib, off, 64);
      if (lane >= off) ib += u;
    }
    ex[lane] = ia - a;
    ex[64 + lane] = total_a + ib - b;
  }
  __syncthreads();
  const int idx = blockIdx.x * 256 + t;
  if (idx < NNODES) {
    int s = start[idx] + ex[blockIdx.x];
    start[idx] = s;
    cursor[idx] = s;
  }
  if (idx == 0) start[NNODES] = NE;
}

// ---------------------------------------------------- CSR build: fill order
__global__ __launch_bounds__(256) void kfill(const int* __restrict__ esrc,
                                             int* __restrict__ cursor,
                                             int* __restrict__ order) {
  int e = blockIdx.x * 256 + threadIdx.x;
  if (e < NE) {
    int p = atomicAdd(&cursor[esrc[e]], 1);
    order[p] = e;
  }
}

// ------- kprep: zero cnt + split weights into fragment-linear planes
__global__ __launch_bounds__(256) void kprep(
    const float* __restrict__ W2a, const float* __restrict__ W2b,
    const float* __restrict__ W2c, const float* __restrict__ Wlin,
    const float* __restrict__ W1, unsigned short* __restrict__ wp,
    int* __restrict__ cnt)
{
  int tid = blockIdx.x * 256 + threadIdx.x;
  for (int i = tid; i < NNODES; i += 7936) cnt[i] = 0;
  if (tid < 7168) {
    int gi = tid;
    const float* W; float sc; unsigned short* outh; int K;
    if (gi < 3072)      { W = W2a; sc = 0.07216878364870323f; outh = wp + W2A_H; K = 192; }
    else if (gi < 5120) { W = W2b; sc = 0.08838834764831845f; outh = wp + W2B_H; K = 128; gi -= 3072; }
    else                { W = W2c; sc = 0.08838834764831845f; outh = wp + W2C_H; K = 128; gi -= 5120; }
    unsigned short* outl = outh + K * 128;
    int l15 = gi & 15, l4 = (gi >> 4) & 3, c16 = (gi >> 6) & 7, kc5 = gi >> 9;
    #pragma unroll
    for (int j = 0; j < 8; ++j) {
      int k = kc5 * 32 + l4 * 8 + j;
      int n = c16 * 16 + l15;
      float v = W[(size_t)k * 128 + n] * sc;
      unsigned short h = f2bf(v);
      outh[gi * 8 + j] = h;
      outl[gi * 8 + j] = f2bf(v - bf2f(h));
    }
  } else if (tid < 7424) {
    int gi = tid - 7168;
    int l15 = gi & 15, l4 = (gi >> 4) & 3, nt = (gi >> 6) & 1, kc2 = gi >> 7;
    #pragma unroll
    for (int j = 0; j < 8; ++j) {
      int k = kc2 * 32 + l4 * 8 + j;
      int n = nt * 16 + l15;
      float v = Wlin[(size_t)k * 32 + n] * 0.125f;
      unsigned short h = f2bf(v);
      wp[WLIN_H + gi * 8 + j] = h;
      wp[WLIN_L + gi * 8 + j] = f2bf(v - bf2f(h));
    }
  } else if (tid < 7936) {
    int gi = tid - 7424;  // W1: 128 x 32, scale 1/sqrt(128)
    int l15 = gi & 15, l4 = (gi >> 4) & 3, nf = (gi >> 6) & 1, kc5 = gi >> 7;
    #pragma unroll
    for (int j = 0; j < 8; ++j) {
      int k = kc5 * 32 + l4 * 8 + j;
      int n = nf * 16 + l15;
      float v = W1[(size_t)k * 32 + n] * 0.08838834764831845f;
      unsigned short h = f2bf(v);
      wp[W1_H + gi * 8 + j] = h;
      wp[W1_L + gi * 8 + j] = f2bf(v - bf2f(h));
    }
  }
}

// -------- k1w: histogram + (w = x@W1/sqrt(128)) via 3-product MFMA (no LDS);
//          w stored bf16; also emits xh hi-plane fragments.
__global__ __launch_bounds__(256) void k1w(
    const float* __restrict__ x, const unsigned short* __restrict__ wp,
    const int* __restrict__ esrc, int* __restrict__ cnt,
    unsigned short* __restrict__ wbufh, unsigned short* __restrict__ xh)
{
  const int t = threadIdx.x;
  const int w = t >> 6, lane = t & 63;
  const int l15 = lane & 15, l4 = lane >> 4;
  const int e0 = blockIdx.x * 128;

  if (t < 128) atomicAdd(&cnt[esrc[e0 + t]], 1);

  f32x4 acc[2][2];
  #pragma unroll
  for (int i = 0; i < 2; ++i)
    #pragma unroll
    for (int j = 0; j < 2; ++j) acc[i][j] = (f32x4)(0.f);

  #pragma unroll
  for (int kc5 = 0; kc5 < 4; ++kc5) {
    short8 bh[2], bl[2];
    #pragma unroll
    for (int nf = 0; nf < 2; ++nf) {
      int idx = (((kc5 * 2 + nf) * 4 + l4) * 16 + l15) * 8;
      bh[nf] = *(const short8*)&wp[W1_H + idx];
      bl[nf] = *(const short8*)&wp[W1_L + idx];
    }
    #pragma unroll
    for (int mf = 0; mf < 2; ++mf) {
      const int row = w * 32 + mf * 16 + l15;
      const float* xp = x + (size_t)(e0 + row) * 128 + kc5 * 32 + l4 * 8;
      float a8[8];
      *(float4*)&a8[0] = *(const float4*)xp;
      *(float4*)&a8[4] = *(const float4*)(xp + 4);
      short8 ah, al;
      #pragma unroll
      for (int j = 0; j < 8; ++j) {
        unsigned short h = f2bf(a8[j]);
        ah[j] = (short)h;
        al[j] = (short)f2bf(a8[j] - bf2f(h));
      }
      *(uint4*)&xh[(size_t)blockIdx.x * 16384 + kc5 * 4096 +
                   (w * 2 + mf) * 512 + l4 * 128 + l15 * 8] = *(uint4*)&ah;
      #pragma unroll
      for (int nf = 0; nf < 2; ++nf) {
        acc[mf][nf] = __builtin_amdgcn_mfma_f32_16x16x32_bf16(ah, bh[nf], acc[mf][nf], 0, 0, 0);
        acc[mf][nf] = __builtin_amdgcn_mfma_f32_16x16x32_bf16(ah, bl[nf], acc[mf][nf], 0, 0, 0);
        acc[mf][nf] = __builtin_amdgcn_mfma_f32_16x16x32_bf16(al, bh[nf], acc[mf][nf], 0, 0, 0);
      }
    }
  }
  #pragma unroll
  for (int mf = 0; mf < 2; ++mf)
    #pragma unroll
    for (int nf = 0; nf < 2; ++nf)
      #pragma unroll
      for (int rr = 0; rr < 4; ++rr) {
        int row = e0 + w * 32 + mf * 16 + l4 * 4 + rr;
        wbufh[(size_t)row * 32 + nf * 16 + l15] = f2bf(acc[mf][nf][rr]);
      }
}

// ---- k_agg: gather reduction, 4 nodes/block (1 wave per node); agg packed bf16
__global__ __launch_bounds__(256) void k_agg(
    const unsigned short* __restrict__ wbufh, const float* __restrict__ Y,
    const int* __restrict__ start, const int* __restrict__ order,
    unsigned short* __restrict__ aggh)
{
  const int t = threadIdx.x;
  const int n = blockIdx.x * 4 + (t >> 6);
  const int lane = t & 63;
  const int c = lane & 31;
  const int dh = lane >> 5;
  if (n >= NNODES) return;
  const int s0 = start[n], s1 = start[n + 1];
  float a0 = 0.f, a1 = 0.f;
  for (int i = s0; i < s1; ++i) {
    int e = order[i];
    float wv = bf2f(wbufh[(size_t)e * 32 + c]);
    float y0 = Y[e * 4 + dh * 2 + 0];
    float y1 = Y[e * 4 + dh * 2 + 1];
    a0 += wv * y0;
    a1 += wv * y1;
  }
  *(unsigned int*)&aggh[(size_t)n * 128 + c * 4 + dh * 2] = cvtpk(a0, a1);
}

// =================== fused: mix + vout + 3-stage MLP + env ===================
// BM=64, 4 waves, wave tile 32x64. LDS 32 KB in two 16 KB regions, 3 barriers.
// (R15-proven version: launch_bounds(256,4), aggh gather hoisted, V inline.)
__global__ __launch_bounds__(256, 4) void kfused(
    const unsigned short* __restrict__ xh, const float* __restrict__ V,
    const float* __restrict__ r, const int* __restrict__ esrc,
    const unsigned short* __restrict__ aggh, const unsigned short* __restrict__ wp,
    float* __restrict__ xout, float* __restrict__ vout)
{
  __shared__ __align__(16) char lds[32768];

  const int t = threadIdx.x;
  const int w = t >> 6, lane = t & 63;
  const int wr = w >> 1, wc = w & 1;
  const int l15 = lane & 15, l4 = lane >> 4;
  const int e0 = blockIdx.x * 64;
  const size_t T16 = (size_t)(blockIdx.x >> 1) * 16384;
  const int xb1 = blockIdx.x & 1;

  // ---------------- phase A: tensor-product mix (scal -> LDS A, vout -> global)
  {
    const int er = w * 16 + l15;
    const int e = e0 + er;
    const int src = esrc[e];

    // hoist the agg gather for both kc2 chunks (long-latency chain)
    uint4 qa[2][2];
    #pragma unroll
    for (int kc2 = 0; kc2 < 2; ++kc2) {
      const unsigned int* ap =
          (const unsigned int*)(aggh + (size_t)src * 128 + kc2 * 64 + l4 * 16);
      qa[kc2][0] = *(const uint4*)ap;
      qa[kc2][1] = *(const uint4*)(ap + 4);
    }

    f32x4 accv[3][2];
    #pragma unroll
    for (int i = 0; i < 3; ++i)
      #pragma unroll
      for (int nt = 0; nt < 2; ++nt) accv[i][nt] = (f32x4)(0.f);

    #pragma unroll
    for (int kc2 = 0; kc2 < 2; ++kc2) {
      short8 WhF[2], WlF[2];
      #pragma unroll
      for (int nt = 0; nt < 2; ++nt) {
        int idx = ((((kc2 * 2 + nt) * 4 + l4) * 16) + l15) * 8;
        WhF[nt] = *(const short8*)&wp[WLIN_H + idx];
        WlF[nt] = *(const short8*)&wp[WLIN_L + idx];
      }
      float4 av4[4], bv4[4];
      const float* bp = V + (size_t)e * 128 + kc2 * 64 + l4 * 16;
      {
        unsigned int uu[8];
        *(uint4*)&uu[0] = qa[kc2][0];
        *(uint4*)&uu[4] = qa[kc2][1];
        #pragma unroll
        for (int ch = 0; ch < 4; ++ch) {
          bv4[ch] = *(const float4*)(bp + ch * 4);
          av4[ch].x = bf2f_lo(uu[2 * ch]) * 0.25f;
          av4[ch].y = bf2f_hi(uu[2 * ch]) * 0.25f;
          av4[ch].z = bf2f_lo(uu[2 * ch + 1]) * 0.25f;
          av4[ch].w = bf2f_hi(uu[2 * ch + 1]) * 0.25f;
        }
      }
      unsigned int su[4];
      #pragma unroll
      for (int ch = 0; ch < 4; ++ch) {
        float s1 = av4[ch].x * bv4[ch].x;
        float s2 = (av4[ch].y * bv4[ch].y + av4[ch].z * bv4[ch].z +
                    av4[ch].w * bv4[ch].w) * 0.5773502691896258f;
        su[ch] = cvtpk(s1, s2);
      }
      {
        int byte = er * 256 + (kc2 * 32 + l4 * 8) * 2;
        byte ^= (er & 7) << 4;
        *(uint4*)(lds + byte) = *(uint4*)su;
      }
      #pragma unroll
      for (int i = 0; i < 3; ++i) {
        union { unsigned int u[4]; short8 s; } ahu;
        #pragma unroll
        for (int ch = 0; ch < 4; ++ch) {
          float bvi = (i == 0) ? bv4[ch].y : (i == 1) ? bv4[ch].z : bv4[ch].w;
          float avi = (i == 0) ? av4[ch].y : (i == 1) ? av4[ch].z : av4[ch].w;
          ahu.u[ch] = cvtpk(av4[ch].x * bvi, avi * bv4[ch].x);  // (v1, v2)
        }
        #pragma unroll
        for (int nt = 0; nt < 2; ++nt) {
          accv[i][nt] = __builtin_amdgcn_mfma_f32_16x16x32_bf16(ahu.s, WhF[nt], accv[i][nt], 0, 0, 0);
          accv[i][nt] = __builtin_amdgcn_mfma_f32_16x16x32_bf16(ahu.s, WlF[nt], accv[i][nt], 0, 0, 0);
        }
      }
    }
    const int ebase = e0 + w * 16 + l4 * 4;
    #pragma unroll
    for (int nt = 0; nt < 2; ++nt)
      #pragma unroll
      for (int rr = 0; rr < 4; ++rr) {
        float* vp = vout + (size_t)(ebase + rr) * 96 + (nt * 16 + l15) * 3;
        vp[0] = accv[0][nt][rr];
        vp[1] = accv[1][nt][rr];
        vp[2] = accv[2][nt][rr];
      }
  }

  __syncthreads();  // #1: scal visible

  f32x4 acc[2][4];
  const int c16 = wc * 4;

  // ---------------- stage 1: h1 = silu(concat(x, scal) @ W2a / sqrt(192))
  #pragma unroll
  for (int i = 0; i < 2; ++i)
    #pragma unroll
    for (int j = 0; j < 4; ++j) acc[i][j] = (f32x4)(0.f);

  #pragma unroll
  for (int kc5 = 0; kc5 < 6; ++kc5) {
    short8 bh[4];
    #pragma unroll
    for (int nf = 0; nf < 4; ++nf) {
      int idx = (((kc5 * 8 + c16 + nf) * 4 + l4) * 16 + l15) * 8;
      bh[nf] = *(const short8*)&wp[W2A_H + idx];
    }
    #pragma unroll
    for (int mf = 0; mf < 2; ++mf) {
      short8 ah;
      if (kc5 < 4) {
        ah = *(const short8*)&xh[T16 + kc5 * 4096 + xb1 * 2048 +
                                 (wr * 2 + mf) * 512 + l4 * 128 + l15 * 8];
      } else {
        int ar = wr * 32 + mf * 16 + l15;
        int byte = ar * 256 + ((kc5 - 4) * 32 + l4 * 8) * 2;
        byte ^= (ar & 7) << 4;
        ah = *(const short8*)(lds + byte);
      }
      #pragma unroll
      for (int nf = 0; nf < 4; ++nf)
        acc[mf][nf] = __builtin_amdgcn_mfma_f32_16x16x32_bf16(ah, bh[nf], acc[mf][nf], 0, 0, 0);
    }
  }

  // h1 -> region B
  #pragma unroll
  for (int mf = 0; mf < 2; ++mf)
    #pragma unroll
    for (int nf = 0; nf < 4; ++nf)
      #pragma unroll
      for (int rp = 0; rp < 2; ++rp) {
        unsigned int zz = cvtpk(fsilu(acc[mf][nf][2 * rp]), fsilu(acc[mf][nf][2 * rp + 1]));
        #pragma unroll
        for (int rh = 0; rh < 2; ++rh) {
          int row = wr * 32 + mf * 16 + l4 * 4 + 2 * rp + rh;
          int byte = row * 256 + (wc * 64 + nf * 16 + l15) * 2;
          byte ^= (row & 7) << 4;
          *(unsigned short*)(lds + 16384 + byte) = (unsigned short)(zz >> (16 * rh));
        }
      }

  __syncthreads();  // #2: h1 visible

  // ---------------- stage 2: h2 = silu(h1 @ W2b / sqrt(128))
  #pragma unroll
  for (int i = 0; i < 2; ++i)
    #pragma unroll
    for (int j = 0; j < 4; ++j) acc[i][j] = (f32x4)(0.f);

  #pragma unroll
  for (int kc5 = 0; kc5 < 4; ++kc5) {
    short8 bh[4];
    #pragma unroll
    for (int nf = 0; nf < 4; ++nf) {
      int idx = (((kc5 * 8 + c16 + nf) * 4 + l4) * 16 + l15) * 8;
      bh[nf] = *(const short8*)&wp[W2B_H + idx];
    }
    #pragma unroll
    for (int mf = 0; mf < 2; ++mf) {
      int row = wr * 32 + mf * 16 + l15;
      int byte = row * 256 + (kc5 * 32 + l4 * 8) * 2;
      byte ^= (row & 7) << 4;
      short8 ah = *(const short8*)(lds + 16384 + byte);
      #pragma unroll
      for (int nf = 0; nf < 4; ++nf)
        acc[mf][nf] = __builtin_amdgcn_mfma_f32_16x16x32_bf16(ah, bh[nf], acc[mf][nf], 0, 0, 0);
    }
  }

  // h2 -> region A (scal dead)
  #pragma unroll
  for (int mf = 0; mf < 2; ++mf)
    #pragma unroll
    for (int nf = 0; nf < 4; ++nf)
      #pragma unroll
      for (int rp = 0; rp < 2; ++rp) {
        unsigned int zz = cvtpk(fsilu(acc[mf][nf][2 * rp]), fsilu(acc[mf][nf][2 * rp + 1]));
        #pragma unroll
        for (int rh = 0; rh < 2; ++rh) {
          int row = wr * 32 + mf * 16 + l4 * 4 + 2 * rp + rh;
          int byte = row * 256 + (wc * 64 + nf * 16 + l15) * 2;
          byte ^= (row & 7) << 4;
          *(unsigned short*)(lds + byte) = (unsigned short)(zz >> (16 * rh));
        }
      }

  __syncthreads();  // #3: h2 visible

  // ---------------- stage 3: x_out = env(d) * (h2 @ W2c / sqrt(128))
  #pragma unroll
  for (int i = 0; i < 2; ++i)
    #pragma unroll
    for (int j = 0; j < 4; ++j) acc[i][j] = (f32x4)(0.f);

  #pragma unroll
  for (int kc5 = 0; kc5 < 4; ++kc5) {
    short8 bh[4];
    #pragma unroll
    for (int nf = 0; nf < 4; ++nf) {
      int idx = (((kc5 * 8 + c16 + nf) * 4 + l4) * 16 + l15) * 8;
      bh[nf] = *(const short8*)&wp[W2C_H + idx];
    }
    #pragma unroll
    for (int mf = 0; mf < 2; ++mf) {
      int row = wr * 32 + mf * 16 + l15;
      int byte = row * 256 + (kc5 * 32 + l4 * 8) * 2;
      byte ^= (row & 7) << 4;
      short8 ah = *(const short8*)(lds + byte);
      #pragma unroll
      for (int nf = 0; nf < 4; ++nf)
        acc[mf][nf] = __builtin_amdgcn_mfma_f32_16x16x32_bf16(ah, bh[nf], acc[mf][nf], 0, 0, 0);
    }
  }

  #pragma unroll
  for (int mf = 0; mf < 2; ++mf) {
    float env4[4];
    #pragma unroll
    for (int rr = 0; rr < 4; ++rr) {
      int row = e0 + wr * 32 + mf * 16 + l4 * 4 + rr;
      float rx = r[row * 3 + 0];
      float ry = r[row * 3 + 1];
      float rz = r[row * 3 + 2];
      float d2 = rx * rx + ry * ry + rz * rz;
      float d = (d2 == 0.f) ? 1.f : sqrtf(d2);
      float d3 = d * d * d;
      env4[rr] = (d < 1.f) ? (1.f + d3 * d3 * (-28.f + d * (48.f - 21.f * d))) : 0.f;
    }
    #pragma unroll
    for (int nf = 0; nf < 4; ++nf)
      #pragma unroll
      for (int rr = 0; rr < 4; ++rr) {
        int row = e0 + wr * 32 + mf * 16 + l4 * 4 + rr;
        xout[(size_t)row * 128 + wc * 64 + nf * 16 + l15] = acc[mf][nf][rr] * env4[rr];
      }
  }
}

extern "C" void kernel_launch(void* const* d_in, const int* in_sizes, int n_in,
                              void* d_out, int out_size, void* d_ws, size_t ws_size,
                              hipStream_t stream)
{
  const float* x    = (const float*)d_in[0];
  const float* V    = (const float*)d_in[1];
  const float* r    = (const float*)d_in[2];
  const float* Y    = (const float*)d_in[3];
  const int*   es   = (const int*)d_in[4];
  const float* W1   = (const float*)d_in[5];
  const float* W2a  = (const float*)d_in[6];
  const float* W2b  = (const float*)d_in[7];
  const float* W2c  = (const float*)d_in[8];
  const float* Wlin = (const float*)d_in[9];

  float* ws   = (float*)d_ws;
  unsigned short* aggh  = (unsigned short*)ws;             // 3.2M ushort (6.4 MB)
  unsigned short* wbufh = (unsigned short*)(ws + 3200000); // 12.8M ushort
  unsigned short* xh = (unsigned short*)(ws + 16000000);   // 51.2M ushort
  int*   ci   = (int*)(ws + 42000000);
  int*   cnt    = ci;
  int*   startv = ci + 25000;
  int*   cursor = ci + 50008;
  int*   order  = ci + 75008;
  int*   sums   = ci + 480000;                             // 98 ints
  unsigned short* wp = (unsigned short*)(ws + 43000000);   // ~254 KB weight planes
  float* xout = (float*)d_out;
  float* vout = (float*)d_out + 51200000;

  (void)in_sizes; (void)n_in; (void)out_size; (void)ws_size;

  kprep<<<dim3(31), 256, 0, stream>>>(W2a, W2b, W2c, Wlin, W1, wp, cnt);
  k1w<<<dim3(NE / 128), 256, 0, stream>>>(x, wp, es, cnt, wbufh, xh);
  kscanA<<<dim3(98), 256, 0, stream>>>(cnt, startv, sums);
  kscanC<<<dim3(98), 256, 0, stream>>>(sums, startv, cursor);
  kfill<<<dim3((NE + 255) / 256), 256, 0, stream>>>(es, cursor, order);
  k_agg<<<dim3((NNODES + 3) / 4), 256, 0, stream>>>(wbufh, Y, startv, order, aggh);
  kfused<<<dim3(NE / 64), 256, 0, stream>>>(xh, V, r, es, aggh, wp, xout, vout);
}

// Round 18
// 349.371 us; speedup vs baseline: 1.0922x; 1.0504x over previous
//
#include <hip/hip_runtime.h>

#define NE 400000
#define NNODES 25000

typedef __attribute__((ext_vector_type(8))) short short8;
typedef __attribute__((ext_vector_type(4))) float f32x4;

// weight-plane ushort offsets inside wp
#define W2A_H 0
#define W2A_L 24576
#define W2B_H 49152
#define W2B_L 65536
#define W2C_H 81920
#define W2C_L 98304
#define WLIN_H 114688
#define WLIN_L 116736
#define W1_H   118784
#define W1_L   122880

__device__ __forceinline__ unsigned short f2bf(float f) {
  unsigned int u = __float_as_uint(f);
  unsigned int r = u + 0x7fffu + ((u >> 16) & 1u);
  return (unsigned short)(r >> 16);
}
__device__ __forceinline__ float bf2f(unsigned short h) {
  return __uint_as_float(((unsigned int)h) << 16);
}
__device__ __forceinline__ float bf2f_lo(unsigned int u) {
  return __uint_as_float(u << 16);
}
__device__ __forceinline__ float bf2f_hi(unsigned int u) {
  return __uint_as_float(u & 0xFFFF0000u);
}
__device__ __forceinline__ unsigned int cvtpk(float lo, float hi) {
  unsigned int r;
  asm("v_cvt_pk_bf16_f32 %0, %1, %2" : "=v"(r) : "v"(lo), "v"(hi));
  return r;
}
__device__ __forceinline__ float fsilu(float z) {
  return z * __builtin_amdgcn_rcpf(1.f + __expf(-z));
}

// ------------------- hierarchical scan: A (block scans + totals)
__global__ __launch_bounds__(256) void kscanA(const int* __restrict__ cnt,
                                              int* __restrict__ start,
                                              int* __restrict__ sums) {
  __shared__ int wtot[4];
  const int t = threadIdx.x, lane = t & 63, wid = t >> 6;
  const int idx = blockIdx.x * 256 + t;
  int v = (idx < NNODES) ? cnt[idx] : 0;
  int incl = v;
  #pragma unroll
  for (int off = 1; off < 64; off <<= 1) {
    int u = __shfl_up(incl, off, 64);
    if (lane >= off) incl += u;
  }
  if (lane == 63) wtot[wid] = incl;
  __syncthreads();
  int woff = 0;
  #pragma unroll
  for (int i = 0; i < 4; ++i)
    if (i < wid) woff += wtot[i];
  int excl = incl - v + woff;
  if (idx < NNODES) start[idx] = excl;
  if (t == 255) sums[blockIdx.x] = excl + v;
}

// ------------- scan C (merged B): per-block redundant 98-scan + offset apply
__global__ __launch_bounds__(256) void kscanC(const int* __restrict__ sums,
                                              int* __restrict__ start,
                                              int* __restrict__ cursor) {
  __shared__ int ex[128];
  const int t = threadIdx.x, lane = t & 63;
  if (t < 64) {
    int a = (lane < 98) ? sums[lane] : 0;
    int b = (64 + lane < 98) ? sums[64 + lane] : 0;
    int ia = a;
    #pragma unroll
    for (int off = 1; off < 64; off <<= 1) {
      int u = __shfl_up(ia, off, 64);
      if (lane >= off) ia += u;
    }
    int total_a = __shfl(ia, 63, 64);
    int ib = b;
    #pragma unroll
    for (int off = 1; off < 64; off <<= 1) {
      int u = __shfl_up(ib, off, 64);
      if (lane >= off) ib += u;
    }
    ex[lane] = ia - a;
    ex[64 + lane] = total_a + ib - b;
  }
  __syncthreads();
  const int idx = blockIdx.x * 256 + t;
  if (idx < NNODES) {
    int s = start[idx] + ex[blockIdx.x];
    start[idx] = s;
    cursor[idx] = s;
  }
  if (idx == 0) start[NNODES] = NE;
}

// ---------------------------------------------------- CSR build: fill order
__global__ __launch_bounds__(256) void kfill(const int* __restrict__ esrc,
                                             int* __restrict__ cursor,
                                             int* __restrict__ order) {
  int e = blockIdx.x * 256 + threadIdx.x;
  if (e < NE) {
    int p = atomicAdd(&cursor[esrc[e]], 1);
    order[p] = e;
  }
}

// ------- kprep: zero cnt + split weights into fragment-linear planes
__global__ __launch_bounds__(256) void kprep(
    const float* __restrict__ W2a, const float* __restrict__ W2b,
    const float* __restrict__ W2c, const float* __restrict__ Wlin,
    const float* __restrict__ W1, unsigned short* __restrict__ wp,
    int* __restrict__ cnt)
{
  int tid = blockIdx.x * 256 + threadIdx.x;
  for (int i = tid; i < NNODES; i += 7936) cnt[i] = 0;
  if (tid < 7168) {
    int gi = tid;
    const float* W; float sc; unsigned short* outh; int K;
    if (gi < 3072)      { W = W2a; sc = 0.07216878364870323f; outh = wp + W2A_H; K = 192; }
    else if (gi < 5120) { W = W2b; sc = 0.08838834764831845f; outh = wp + W2B_H; K = 128; gi -= 3072; }
    else                { W = W2c; sc = 0.08838834764831845f; outh = wp + W2C_H; K = 128; gi -= 5120; }
    unsigned short* outl = outh + K * 128;
    int l15 = gi & 15, l4 = (gi >> 4) & 3, c16 = (gi >> 6) & 7, kc5 = gi >> 9;
    #pragma unroll
    for (int j = 0; j < 8; ++j) {
      int k = kc5 * 32 + l4 * 8 + j;
      int n = c16 * 16 + l15;
      float v = W[(size_t)k * 128 + n] * sc;
      unsigned short h = f2bf(v);
      outh[gi * 8 + j] = h;
      outl[gi * 8 + j] = f2bf(v - bf2f(h));
    }
  } else if (tid < 7424) {
    int gi = tid - 7168;
    int l15 = gi & 15, l4 = (gi >> 4) & 3, nt = (gi >> 6) & 1, kc2 = gi >> 7;
    #pragma unroll
    for (int j = 0; j < 8; ++j) {
      int k = kc2 * 32 + l4 * 8 + j;
      int n = nt * 16 + l15;
      float v = Wlin[(size_t)k * 32 + n] * 0.125f;
      unsigned short h = f2bf(v);
      wp[WLIN_H + gi * 8 + j] = h;
      wp[WLIN_L + gi * 8 + j] = f2bf(v - bf2f(h));
    }
  } else if (tid < 7936) {
    int gi = tid - 7424;  // W1: 128 x 32, scale 1/sqrt(128)
    int l15 = gi & 15, l4 = (gi >> 4) & 3, nf = (gi >> 6) & 1, kc5 = gi >> 7;
    #pragma unroll
    for (int j = 0; j < 8; ++j) {
      int k = kc5 * 32 + l4 * 8 + j;
      int n = nf * 16 + l15;
      float v = W1[(size_t)k * 32 + n] * 0.08838834764831845f;
      unsigned short h = f2bf(v);
      wp[W1_H + gi * 8 + j] = h;
      wp[W1_L + gi * 8 + j] = f2bf(v - bf2f(h));
    }
  }
}

// -------- k1w: histogram + (w = x@W1/sqrt(128)) via 3-product MFMA (no LDS);
//          w stored bf16; also emits xh hi-plane fragments.
__global__ __launch_bounds__(256) void k1w(
    const float* __restrict__ x, const unsigned short* __restrict__ wp,
    const int* __restrict__ esrc, int* __restrict__ cnt,
    unsigned short* __restrict__ wbufh, unsigned short* __restrict__ xh)
{
  const int t = threadIdx.x;
  const int w = t >> 6, lane = t & 63;
  const int l15 = lane & 15, l4 = lane >> 4;
  const int e0 = blockIdx.x * 128;

  if (t < 128) atomicAdd(&cnt[esrc[e0 + t]], 1);

  f32x4 acc[2][2];
  #pragma unroll
  for (int i = 0; i < 2; ++i)
    #pragma unroll
    for (int j = 0; j < 2; ++j) acc[i][j] = (f32x4)(0.f);

  #pragma unroll
  for (int kc5 = 0; kc5 < 4; ++kc5) {
    short8 bh[2], bl[2];
    #pragma unroll
    for (int nf = 0; nf < 2; ++nf) {
      int idx = (((kc5 * 2 + nf) * 4 + l4) * 16 + l15) * 8;
      bh[nf] = *(const short8*)&wp[W1_H + idx];
      bl[nf] = *(const short8*)&wp[W1_L + idx];
    }
    #pragma unroll
    for (int mf = 0; mf < 2; ++mf) {
      const int row = w * 32 + mf * 16 + l15;
      const float* xp = x + (size_t)(e0 + row) * 128 + kc5 * 32 + l4 * 8;
      float a8[8];
      *(float4*)&a8[0] = *(const float4*)xp;
      *(float4*)&a8[4] = *(const float4*)(xp + 4);
      short8 ah, al;
      #pragma unroll
      for (int j = 0; j < 8; ++j) {
        unsigned short h = f2bf(a8[j]);
        ah[j] = (short)h;
        al[j] = (short)f2bf(a8[j] - bf2f(h));
      }
      *(uint4*)&xh[(size_t)blockIdx.x * 16384 + kc5 * 4096 +
                   (w * 2 + mf) * 512 + l4 * 128 + l15 * 8] = *(uint4*)&ah;
      #pragma unroll
      for (int nf = 0; nf < 2; ++nf) {
        acc[mf][nf] = __builtin_amdgcn_mfma_f32_16x16x32_bf16(ah, bh[nf], acc[mf][nf], 0, 0, 0);
        acc[mf][nf] = __builtin_amdgcn_mfma_f32_16x16x32_bf16(ah, bl[nf], acc[mf][nf], 0, 0, 0);
        acc[mf][nf] = __builtin_amdgcn_mfma_f32_16x16x32_bf16(al, bh[nf], acc[mf][nf], 0, 0, 0);
      }
    }
  }
  #pragma unroll
  for (int mf = 0; mf < 2; ++mf)
    #pragma unroll
    for (int nf = 0; nf < 2; ++nf)
      #pragma unroll
      for (int rr = 0; rr < 4; ++rr) {
        int row = e0 + w * 32 + mf * 16 + l4 * 4 + rr;
        wbufh[(size_t)row * 32 + nf * 16 + l15] = f2bf(acc[mf][nf][rr]);
      }
}

// ---- k_agg: per-node gather reduction (1 wave/node); agg stored packed bf16
__global__ __launch_bounds__(64) void k_agg(
    const unsigned short* __restrict__ wbufh, const float* __restrict__ Y,
    const int* __restrict__ start, const int* __restrict__ order,
    unsigned short* __restrict__ aggh)
{
  const int n = blockIdx.x;
  const int t = threadIdx.x;
  const int c = t & 31;
  const int dh = t >> 5;
  const int s0 = start[n], s1 = start[n + 1];
  float a0 = 0.f, a1 = 0.f;
  for (int i = s0; i < s1; ++i) {
    int e = order[i];
    float wv = bf2f(wbufh[(size_t)e * 32 + c]);
    float y0 = Y[e * 4 + dh * 2 + 0];
    float y1 = Y[e * 4 + dh * 2 + 1];
    a0 += wv * y0;
    a1 += wv * y1;
  }
  *(unsigned int*)&aggh[(size_t)n * 128 + c * 4 + dh * 2] = cvtpk(a0, a1);
}

// =================== fused: mix + vout + 3-stage MLP + env ===================
// BM=64, 4 waves, wave tile 32x64. LDS 32 KB in two 16 KB regions, 3 barriers.
// (R15-proven: launch_bounds(256,4), aggh gather hoisted, V inline.)
__global__ __launch_bounds__(256, 4) void kfused(
    const unsigned short* __restrict__ xh, const float* __restrict__ V,
    const float* __restrict__ r, const int* __restrict__ esrc,
    const unsigned short* __restrict__ aggh, const unsigned short* __restrict__ wp,
    float* __restrict__ xout, float* __restrict__ vout)
{
  __shared__ __align__(16) char lds[32768];

  const int t = threadIdx.x;
  const int w = t >> 6, lane = t & 63;
  const int wr = w >> 1, wc = w & 1;
  const int l15 = lane & 15, l4 = lane >> 4;
  const int e0 = blockIdx.x * 64;
  const size_t T16 = (size_t)(blockIdx.x >> 1) * 16384;
  const int xb1 = blockIdx.x & 1;

  // ---------------- phase A: tensor-product mix (scal -> LDS A, vout -> global)
  {
    const int er = w * 16 + l15;
    const int e = e0 + er;
    const int src = esrc[e];

    // hoist the agg gather for both kc2 chunks (long-latency chain)
    uint4 qa[2][2];
    #pragma unroll
    for (int kc2 = 0; kc2 < 2; ++kc2) {
      const unsigned int* ap =
          (const unsigned int*)(aggh + (size_t)src * 128 + kc2 * 64 + l4 * 16);
      qa[kc2][0] = *(const uint4*)ap;
      qa[kc2][1] = *(const uint4*)(ap + 4);
    }

    f32x4 accv[3][2];
    #pragma unroll
    for (int i = 0; i < 3; ++i)
      #pragma unroll
      for (int nt = 0; nt < 2; ++nt) accv[i][nt] = (f32x4)(0.f);

    #pragma unroll
    for (int kc2 = 0; kc2 < 2; ++kc2) {
      short8 WhF[2], WlF[2];
      #pragma unroll
      for (int nt = 0; nt < 2; ++nt) {
        int idx = ((((kc2 * 2 + nt) * 4 + l4) * 16) + l15) * 8;
        WhF[nt] = *(const short8*)&wp[WLIN_H + idx];
        WlF[nt] = *(const short8*)&wp[WLIN_L + idx];
      }
      float4 av4[4], bv4[4];
      const float* bp = V + (size_t)e * 128 + kc2 * 64 + l4 * 16;
      {
        unsigned int uu[8];
        *(uint4*)&uu[0] = qa[kc2][0];
        *(uint4*)&uu[4] = qa[kc2][1];
        #pragma unroll
        for (int ch = 0; ch < 4; ++ch) {
          bv4[ch] = *(const float4*)(bp + ch * 4);
          av4[ch].x = bf2f_lo(uu[2 * ch]) * 0.25f;
          av4[ch].y = bf2f_hi(uu[2 * ch]) * 0.25f;
          av4[ch].z = bf2f_lo(uu[2 * ch + 1]) * 0.25f;
          av4[ch].w = bf2f_hi(uu[2 * ch + 1]) * 0.25f;
        }
      }
      unsigned int su[4];
      #pragma unroll
      for (int ch = 0; ch < 4; ++ch) {
        float s1 = av4[ch].x * bv4[ch].x;
        float s2 = (av4[ch].y * bv4[ch].y + av4[ch].z * bv4[ch].z +
                    av4[ch].w * bv4[ch].w) * 0.5773502691896258f;
        su[ch] = cvtpk(s1, s2);
      }
      {
        int byte = er * 256 + (kc2 * 32 + l4 * 8) * 2;
        byte ^= (er & 7) << 4;
        *(uint4*)(lds + byte) = *(uint4*)su;
      }
      #pragma unroll
      for (int i = 0; i < 3; ++i) {
        union { unsigned int u[4]; short8 s; } ahu;
        #pragma unroll
        for (int ch = 0; ch < 4; ++ch) {
          float bvi = (i == 0) ? bv4[ch].y : (i == 1) ? bv4[ch].z : bv4[ch].w;
          float avi = (i == 0) ? av4[ch].y : (i == 1) ? av4[ch].z : av4[ch].w;
          ahu.u[ch] = cvtpk(av4[ch].x * bvi, avi * bv4[ch].x);  // (v1, v2)
        }
        #pragma unroll
        for (int nt = 0; nt < 2; ++nt) {
          accv[i][nt] = __builtin_amdgcn_mfma_f32_16x16x32_bf16(ahu.s, WhF[nt], accv[i][nt], 0, 0, 0);
          accv[i][nt] = __builtin_amdgcn_mfma_f32_16x16x32_bf16(ahu.s, WlF[nt], accv[i][nt], 0, 0, 0);
        }
      }
    }
    const int ebase = e0 + w * 16 + l4 * 4;
    #pragma unroll
    for (int nt = 0; nt < 2; ++nt)
      #pragma unroll
      for (int rr = 0; rr < 4; ++rr) {
        float* vp = vout + (size_t)(ebase + rr) * 96 + (nt * 16 + l15) * 3;
        vp[0] = accv[0][nt][rr];
        vp[1] = accv[1][nt][rr];
        vp[2] = accv[2][nt][rr];
      }
  }

  __syncthreads();  // #1: scal visible

  f32x4 acc[2][4];
  const int c16 = wc * 4;

  // ---------------- stage 1: h1 = silu(concat(x, scal) @ W2a / sqrt(192))
  #pragma unroll
  for (int i = 0; i < 2; ++i)
    #pragma unroll
    for (int j = 0; j < 4; ++j) acc[i][j] = (f32x4)(0.f);

  #pragma unroll
  for (int kc5 = 0; kc5 < 6; ++kc5) {
    short8 bh[4];
    #pragma unroll
    for (int nf = 0; nf < 4; ++nf) {
      int idx = (((kc5 * 8 + c16 + nf) * 4 + l4) * 16 + l15) * 8;
      bh[nf] = *(const short8*)&wp[W2A_H + idx];
    }
    #pragma unroll
    for (int mf = 0; mf < 2; ++mf) {
      short8 ah;
      if (kc5 < 4) {
        ah = *(const short8*)&xh[T16 + kc5 * 4096 + xb1 * 2048 +
                                 (wr * 2 + mf) * 512 + l4 * 128 + l15 * 8];
      } else {
        int ar = wr * 32 + mf * 16 + l15;
        int byte = ar * 256 + ((kc5 - 4) * 32 + l4 * 8) * 2;
        byte ^= (ar & 7) << 4;
        ah = *(const short8*)(lds + byte);
      }
      #pragma unroll
      for (int nf = 0; nf < 4; ++nf)
        acc[mf][nf] = __builtin_amdgcn_mfma_f32_16x16x32_bf16(ah, bh[nf], acc[mf][nf], 0, 0, 0);
    }
  }

  // h1 -> region B
  #pragma unroll
  for (int mf = 0; mf < 2; ++mf)
    #pragma unroll
    for (int nf = 0; nf < 4; ++nf)
      #pragma unroll
      for (int rp = 0; rp < 2; ++rp) {
        unsigned int zz = cvtpk(fsilu(acc[mf][nf][2 * rp]), fsilu(acc[mf][nf][2 * rp + 1]));
        #pragma unroll
        for (int rh = 0; rh < 2; ++rh) {
          int row = wr * 32 + mf * 16 + l4 * 4 + 2 * rp + rh;
          int byte = row * 256 + (wc * 64 + nf * 16 + l15) * 2;
          byte ^= (row & 7) << 4;
          *(unsigned short*)(lds + 16384 + byte) = (unsigned short)(zz >> (16 * rh));
        }
      }

  __syncthreads();  // #2: h1 visible

  // ---------------- stage 2: h2 = silu(h1 @ W2b / sqrt(128))
  #pragma unroll
  for (int i = 0; i < 2; ++i)
    #pragma unroll
    for (int j = 0; j < 4; ++j) acc[i][j] = (f32x4)(0.f);

  #pragma unroll
  for (int kc5 = 0; kc5 < 4; ++kc5) {
    short8 bh[4];
    #pragma unroll
    for (int nf = 0; nf < 4; ++nf) {
      int idx = (((kc5 * 8 + c16 + nf) * 4 + l4) * 16 + l15) * 8;
      bh[nf] = *(const short8*)&wp[W2B_H + idx];
    }
    #pragma unroll
    for (int mf = 0; mf < 2; ++mf) {
      int row = wr * 32 + mf * 16 + l15;
      int byte = row * 256 + (kc5 * 32 + l4 * 8) * 2;
      byte ^= (row & 7) << 4;
      short8 ah = *(const short8*)(lds + 16384 + byte);
      #pragma unroll
      for (int nf = 0; nf < 4; ++nf)
        acc[mf][nf] = __builtin_amdgcn_mfma_f32_16x16x32_bf16(ah, bh[nf], acc[mf][nf], 0, 0, 0);
    }
  }

  // h2 -> region A (scal dead)
  #pragma unroll
  for (int mf = 0; mf < 2; ++mf)
    #pragma unroll
    for (int nf = 0; nf < 4; ++nf)
      #pragma unroll
      for (int rp = 0; rp < 2; ++rp) {
        unsigned int zz = cvtpk(fsilu(acc[mf][nf][2 * rp]), fsilu(acc[mf][nf][2 * rp + 1]));
        #pragma unroll
        for (int rh = 0; rh < 2; ++rh) {
          int row = wr * 32 + mf * 16 + l4 * 4 + 2 * rp + rh;
          int byte = row * 256 + (wc * 64 + nf * 16 + l15) * 2;
          byte ^= (row & 7) << 4;
          *(unsigned short*)(lds + byte) = (unsigned short)(zz >> (16 * rh));
        }
      }

  __syncthreads();  // #3: h2 visible

  // ---------------- stage 3: x_out = env(d) * (h2 @ W2c / sqrt(128))
  #pragma unroll
  for (int i = 0; i < 2; ++i)
    #pragma unroll
    for (int j = 0; j < 4; ++j) acc[i][j] = (f32x4)(0.f);

  #pragma unroll
  for (int kc5 = 0; kc5 < 4; ++kc5) {
    short8 bh[4];
    #pragma unroll
    for (int nf = 0; nf < 4; ++nf) {
      int idx = (((kc5 * 8 + c16 + nf) * 4 + l4) * 16 + l15) * 8;
      bh[nf] = *(const short8*)&wp[W2C_H + idx];
    }
    #pragma unroll
    for (int mf = 0; mf < 2; ++mf) {
      int row = wr * 32 + mf * 16 + l15;
      int byte = row * 256 + (kc5 * 32 + l4 * 8) * 2;
      byte ^= (row & 7) << 4;
      short8 ah = *(const short8*)(lds + byte);
      #pragma unroll
      for (int nf = 0; nf < 4; ++nf)
        acc[mf][nf] = __builtin_amdgcn_mfma_f32_16x16x32_bf16(ah, bh[nf], acc[mf][nf], 0, 0, 0);
    }
  }

  #pragma unroll
  for (int mf = 0; mf < 2; ++mf) {
    float env4[4];
    #pragma unroll
    for (int rr = 0; rr < 4; ++rr) {
      int row = e0 + wr * 32 + mf * 16 + l4 * 4 + rr;
      float rx = r[row * 3 + 0];
      float ry = r[row * 3 + 1];
      float rz = r[row * 3 + 2];
      float d2 = rx * rx + ry * ry + rz * rz;
      float d = (d2 == 0.f) ? 1.f : sqrtf(d2);
      float d3 = d * d * d;
      env4[rr] = (d < 1.f) ? (1.f + d3 * d3 * (-28.f + d * (48.f - 21.f * d))) : 0.f;
    }
    #pragma unroll
    for (int nf = 0; nf < 4; ++nf)
      #pragma unroll
      for (int rr = 0; rr < 4; ++rr) {
        int row = e0 + wr * 32 + mf * 16 + l4 * 4 + rr;
        xout[(size_t)row * 128 + wc * 64 + nf * 16 + l15] = acc[mf][nf][rr] * env4[rr];
      }
  }
}

extern "C" void kernel_launch(void* const* d_in, const int* in_sizes, int n_in,
                              void* d_out, int out_size, void* d_ws, size_t ws_size,
                              hipStream_t stream)
{
  const float* x    = (const float*)d_in[0];
  const float* V    = (const float*)d_in[1];
  const float* r    = (const float*)d_in[2];
  const float* Y    = (const float*)d_in[3];
  const int*   es   = (const int*)d_in[4];
  const float* W1   = (const float*)d_in[5];
  const float* W2a  = (const float*)d_in[6];
  const float* W2b  = (const float*)d_in[7];
  const float* W2c  = (const float*)d_in[8];
  const float* Wlin = (const float*)d_in[9];

  float* ws   = (float*)d_ws;
  unsigned short* aggh  = (unsigned short*)ws;             // 3.2M ushort (6.4 MB)
  unsigned short* wbufh = (unsigned short*)(ws + 3200000); // 12.8M ushort
  unsigned short* xh = (unsigned short*)(ws + 16000000);   // 51.2M ushort
  int*   ci   = (int*)(ws + 42000000);
  int*   cnt    = ci;
  int*   startv = ci + 25000;
  int*   cursor = ci + 50008;
  int*   order  = ci + 75008;
  int*   sums   = ci + 480000;                             // 98 ints
  unsigned short* wp = (unsigned short*)(ws + 43000000);   // ~254 KB weight planes
  float* xout = (float*)d_out;
  float* vout = (float*)d_out + 51200000;

  (void)in_sizes; (void)n_in; (void)out_size; (void)ws_size;

  kprep<<<dim3(31), 256, 0, stream>>>(W2a, W2b, W2c, Wlin, W1, wp, cnt);
  k1w<<<dim3(NE / 128), 256, 0, stream>>>(x, wp, es, cnt, wbufh, xh);
  kscanA<<<dim3(98), 256, 0, stream>>>(cnt, startv, sums);
  kscanC<<<dim3(98), 256, 0, stream>>>(sums, startv, cursor);
  kfill<<<dim3((NE + 255) / 256), 256, 0, stream>>>(es, cursor, order);
  k_agg<<<dim3(NNODES), 64, 0, stream>>>(wbufh, Y, startv, order, aggh);
  kfused<<<dim3(NE / 64), 256, 0, stream>>>(xh, V, r, es, aggh, wp, xout, vout);
}